// Round 9
// baseline (132.885 us; speedup 1.0000x reference)
//
#include <hip/hip_runtime.h>
#include <math.h>

// LocalAttention: B=2, T=2048, C=512, WINDOW=32
#define BB 2
#define TT 2048
#define CC 512
#define WIN 32
#define WSZ 63            // 2*WIN-1
#define MM (BB * TT)      // 4096
#define QKLD 1024         // qkv intermediate row stride (Q | K only)

typedef __attribute__((ext_vector_type(8))) short short8;
typedef __attribute__((ext_vector_type(4))) float floatx4;

__device__ inline unsigned short bf16_rn(float f) {
  unsigned u = __builtin_bit_cast(unsigned, f);
  u += 0x7fff + ((u >> 16) & 1);
  return (unsigned short)(u >> 16);
}
__device__ inline unsigned pack_bf16x2(float lo, float hi) {
  return (unsigned)bf16_rn(lo) | ((unsigned)bf16_rn(hi) << 16);
}

// ---------------------------------------------------------------------------
// Pre-convert fp32 inputs -> bf16 (x, w_qkv, w_proj). 8 elems/thread.
// ---------------------------------------------------------------------------
#define NX  (MM * CC)          // 2097152
#define NWQ (3 * CC * CC)      // 786432
#define NWP (CC * CC)          // 262144

__global__ __launch_bounds__(256) void convert_bf16(
    const float* __restrict__ x, const float* __restrict__ wq,
    const float* __restrict__ wp, ushort* __restrict__ xb,
    ushort* __restrict__ wqb, ushort* __restrict__ wpb) {
  const size_t e = ((size_t)blockIdx.x * 256 + threadIdx.x) * 8;
  const float* src;
  ushort* dst;
  size_t off;
  if (e < NX) { src = x; dst = xb; off = e; }
  else if (e < NX + NWQ) { src = wq; dst = wqb; off = e - NX; }
  else { src = wp; dst = wpb; off = e - NX - NWQ; }
  float4 v0 = ((const float4*)(src + off))[0];
  float4 v1 = ((const float4*)(src + off))[1];
  uint4 o;
  o.x = pack_bf16x2(v0.x, v0.y);
  o.y = pack_bf16x2(v0.z, v0.w);
  o.z = pack_bf16x2(v1.x, v1.y);
  o.w = pack_bf16x2(v1.z, v1.w);
  *(uint4*)(dst + off) = o;
}

// ---------------------------------------------------------------------------
// Barrier-light NT GEMM for QKV (r7 structure, best measured). BM=128, BN=64,
// K=512 fixed. B-panel (64 n x 256 k bf16) staged in LDS once per k-half ->
// 3 barriers per block, no per-K-step drain. A fragments direct from global.
// Q,K tiles (n0 < 1024) -> qkv rows with stride QKLD; V tiles (n0 >= 1024)
// -> bias+bf16, LDS transpose, coalesced VT[n][m] row writes.
// ---------------------------------------------------------------------------
#define PSTR 264   // B-panel k-stride (elems); 528B rows
#define VSTR 136   // V-transpose m-stride (elems)

__global__ __launch_bounds__(256) void gemm_qkv(
    const ushort* __restrict__ A, const ushort* __restrict__ B,
    const float* __restrict__ bias, ushort* __restrict__ C,
    ushort* __restrict__ VT) {
  __shared__ __align__(16) ushort Bs[64 * PSTR];  // 33792 B

  const int tid = threadIdx.x;
  const int lane = tid & 63;
  const int wave = tid >> 6;
  const int m0 = blockIdx.y * 128;
  const int n0 = blockIdx.x * 64;
  const int wm = wave * 32;
  const int mlane = lane & 15, quad = lane >> 4;

  floatx4 acc[2][4];
#pragma unroll
  for (int i = 0; i < 2; ++i)
#pragma unroll
    for (int j = 0; j < 4; ++j) acc[i][j] = (floatx4){0.f, 0.f, 0.f, 0.f};

  for (int h = 0; h < 2; ++h) {
    if (h) __syncthreads();
    // stage B panel half: 64 rows x 256 k = 2048 uint4, coalesced
#pragma unroll
    for (int i = 0; i < 8; ++i) {
      const int idx = tid + 256 * i;
      const int r = idx >> 5, kc = (idx & 31) * 8;
      *(uint4*)(&Bs[r * PSTR + kc]) =
          *(const uint4*)(B + (size_t)(n0 + r) * CC + h * 256 + kc);
    }
    __syncthreads();
#pragma unroll
    for (int ks = 0; ks < 8; ++ks) {
      short8 bfr[4];
#pragma unroll
      for (int ni = 0; ni < 4; ++ni)
        bfr[ni] = *(const short8*)(&Bs[(ni * 16 + mlane) * PSTR + ks * 32 + quad * 8]);
#pragma unroll
      for (int mi = 0; mi < 2; ++mi) {
        short8 af = *(const short8*)(
            A + (size_t)(m0 + wm + mi * 16 + mlane) * CC + h * 256 + ks * 32 + quad * 8);
#pragma unroll
        for (int ni = 0; ni < 4; ++ni)
          acc[mi][ni] = __builtin_amdgcn_mfma_f32_16x16x32_bf16(af, bfr[ni], acc[mi][ni], 0, 0, 0);
      }
    }
  }

  // epilogue: D row = quad*4 + r (m), col = mlane (n)
  if (n0 < 1024) {  // Q,K path -> qkv rows (stride QKLD)
#pragma unroll
    for (int ni = 0; ni < 4; ++ni) {
      const int n = n0 + ni * 16 + mlane;
      const float bn = bias[n];
#pragma unroll
      for (int mi = 0; mi < 2; ++mi) {
        const int mbase = m0 + wm + mi * 16 + quad * 4;
#pragma unroll
        for (int r = 0; r < 4; ++r)
          C[(size_t)(mbase + r) * QKLD + n] = bf16_rn(acc[mi][ni][r] + bn);
      }
    }
  } else {  // V path: transpose through LDS, coalesced VT[n][m] rows
    ushort* Vt = Bs;  // alias; 64 x VSTR = 17408 B
    __syncthreads();
#pragma unroll
    for (int ni = 0; ni < 4; ++ni) {
      const int n_l = ni * 16 + mlane;
      const float bn = bias[n0 + n_l];
#pragma unroll
      for (int mi = 0; mi < 2; ++mi) {
        const int m_l = wm + mi * 16 + quad * 4;
        ushort4 pk;
        pk.x = bf16_rn(acc[mi][ni][0] + bn);
        pk.y = bf16_rn(acc[mi][ni][1] + bn);
        pk.z = bf16_rn(acc[mi][ni][2] + bn);
        pk.w = bf16_rn(acc[mi][ni][3] + bn);
        *(ushort4*)(&Vt[n_l * VSTR + m_l]) = pk;
      }
    }
    __syncthreads();
#pragma unroll
    for (int i = 0; i < 4; ++i) {  // 64 rows x 16 uint4
      const int idx = tid + 256 * i;
      const int n_l = idx >> 4, mo = (idx & 15) * 8;
      *(uint4*)(VT + (size_t)(n0 - 1024 + n_l) * MM + m0 + mo) =
          *(const uint4*)(&Vt[n_l * VSTR + mo]);
    }
  }
}

// ---------------------------------------------------------------------------
// Fused banded attention + output projection. Block = 8 tokens, grid 512.
//  S = Q.K^T (direct-global fragments, dual MFMA chains), softmax -> P (LDS),
//  PV with V from pre-transposed vT[c][m] -> attn tile to LDS (bf16),
//  then proj: out[16x512] = at @ w_proj^T + b_proj, A-frags from LDS,
//  B-frags direct from L2-resident bf16 w_proj. Rows 8..15 are finite
//  don't-cares, masked at the final fp32 store.
// OOB reads fault-safe via ws guards; garbage lands in masked/P=0 positions.
// ---------------------------------------------------------------------------
#define ATILE 8
#define SLD 84    // S row stride (floats)
#define PLD 104   // P row stride (ushorts), odd granules
#define ATS 520   // attn-tile row stride (ushorts), 65 granules (odd)

__global__ __launch_bounds__(256) void attn_proj(
    const ushort* __restrict__ qkv, const ushort* __restrict__ vT,
    const ushort* __restrict__ wpb, const float* __restrict__ bproj,
    float* __restrict__ out) {
  __shared__ __align__(16) float s_s[16 * SLD];    //  5376 B
  __shared__ __align__(16) ushort p_s[16 * PLD];   //  3328 B
  __shared__ __align__(16) ushort at_s[16 * ATS];  // 16640 B

  const int tid = threadIdx.x;
  const int wave = tid >> 6, lane = tid & 63;
  const int mlane = lane & 15, quad = lane >> 4;
  const int bt0 = blockIdx.x * ATILE;
  const int b = bt0 / TT, t0 = bt0 % TT;
  const ushort* qbase = qkv + (size_t)b * TT * QKLD;

  // ---- scores: S[16][80] = Q.K^T, dual chains ----
  const ushort* qrow  = qbase + (ptrdiff_t)(t0 + mlane) * QKLD;
  const ushort* krow0 = qbase + (ptrdiff_t)(t0 - 32 + wave * 16 + mlane) * QKLD + CC;
  const ushort* krow1 = qbase + (ptrdiff_t)(t0 - 32 + 64 + mlane) * QKLD + CC;
  floatx4 s0a = (floatx4){0.f, 0.f, 0.f, 0.f}, s0b = s0a;
  floatx4 s1a = s0a, s1b = s0a;
#pragma unroll
  for (int ks = 0; ks < 16; ++ks) {
    short8 a  = *(const short8*)(qrow + ks * 32 + quad * 8);
    short8 b0 = *(const short8*)(krow0 + ks * 32 + quad * 8);
    if (ks & 1) s0b = __builtin_amdgcn_mfma_f32_16x16x32_bf16(a, b0, s0b, 0, 0, 0);
    else        s0a = __builtin_amdgcn_mfma_f32_16x16x32_bf16(a, b0, s0a, 0, 0, 0);
    if (wave == 0) {  // wave-uniform: wave0 also owns col-tile 4
      short8 b1 = *(const short8*)(krow1 + ks * 32 + quad * 8);
      if (ks & 1) s1b = __builtin_amdgcn_mfma_f32_16x16x32_bf16(a, b1, s1b, 0, 0, 0);
      else        s1a = __builtin_amdgcn_mfma_f32_16x16x32_bf16(a, b1, s1a, 0, 0, 0);
    }
  }

#pragma unroll
  for (int r = 0; r < 4; ++r)
    s_s[(quad * 4 + r) * SLD + wave * 16 + mlane] = s0a[r] + s0b[r];
  if (wave == 0) {
#pragma unroll
    for (int r = 0; r < 4; ++r)
      s_s[(quad * 4 + r) * SLD + 64 + mlane] = s1a[r] + s1b[r];
  }
  __syncthreads();

  // ---- softmax: 16 rows x 16 lanes, 5 cols each; mask j = r-1-row ----
  {
    const int row = tid >> 4, li = tid & 15;
    const float inv_scale = 0.044194173824159216f;  // 512^-0.5
    float e[5];
    float mx = -INFINITY;
#pragma unroll
    for (int i = 0; i < 5; ++i) {
      const int r = li + 16 * i;
      const int j = r - 1 - row;
      const int src = t0 - 32 + r;
      const bool valid = (j >= 0) && (j < WSZ) && (src >= 0) && (src < TT);
      e[i] = valid ? s_s[row * SLD + r] * inv_scale : -INFINITY;
      mx = fmaxf(mx, e[i]);
    }
    mx = fmaxf(mx, __shfl_xor(mx, 1)); mx = fmaxf(mx, __shfl_xor(mx, 2));
    mx = fmaxf(mx, __shfl_xor(mx, 4)); mx = fmaxf(mx, __shfl_xor(mx, 8));
    float sum = 0.f;
#pragma unroll
    for (int i = 0; i < 5; ++i) {
      e[i] = (e[i] == -INFINITY) ? 0.f : __expf(e[i] - mx);
      sum += e[i];
    }
    sum += __shfl_xor(sum, 1); sum += __shfl_xor(sum, 2);
    sum += __shfl_xor(sum, 4); sum += __shfl_xor(sum, 8);
    const float rs = 1.f / sum;
#pragma unroll
    for (int i = 0; i < 5; ++i)
      p_s[row * PLD + li + 16 * i] = bf16_rn(e[i] * rs);
    if (li < 8) {  // zero k-pad cols 80..103 (PV k-extent is 96)
      p_s[row * PLD + 80 + li] = 0;
      p_s[row * PLD + 88 + li] = 0;
      p_s[row * PLD + 96 + li] = 0;
    }
  }
  __syncthreads();

  // ---- PV: at[16][512] = P.V, V direct from vT[c][m]; result -> LDS ----
  const ptrdiff_t mcol0 = (ptrdiff_t)b * TT + t0 - 32;
  {
    short8 pa[3];
#pragma unroll
    for (int ks = 0; ks < 3; ++ks)
      pa[ks] = *(const short8*)(&p_s[mlane * PLD + ks * 32 + quad * 8]);
#pragma unroll
    for (int nt8 = 0; nt8 < 8; ++nt8) {
      const int nt = wave * 8 + nt8;
      const ushort* vrow = vT + (ptrdiff_t)(nt * 16 + mlane) * MM + mcol0;
      floatx4 o = (floatx4){0.f, 0.f, 0.f, 0.f};
#pragma unroll
      for (int ks = 0; ks < 3; ++ks) {
        short8 bv = *(const short8*)(vrow + ks * 32 + quad * 8);
        o = __builtin_amdgcn_mfma_f32_16x16x32_bf16(pa[ks], bv, o, 0, 0, 0);
      }
#pragma unroll
      for (int r = 0; r < 4; ++r)
        at_s[(quad * 4 + r) * ATS + nt * 16 + mlane] = bf16_rn(o[r]);
    }
  }
  __syncthreads();

  // ---- proj: out[16][512] = at @ w_proj^T + b_proj ----
  {
    short8 af[16];
#pragma unroll
    for (int ks = 0; ks < 16; ++ks)
      af[ks] = *(const short8*)(&at_s[mlane * ATS + ks * 32 + quad * 8]);
#pragma unroll
    for (int i = 0; i < 8; ++i) {
      const int n = (wave * 8 + i) * 16 + mlane;
      const ushort* wrow = wpb + (size_t)n * CC;
      floatx4 o = (floatx4){0.f, 0.f, 0.f, 0.f};
#pragma unroll
      for (int ks = 0; ks < 16; ++ks) {
        short8 bfr = *(const short8*)(wrow + ks * 32 + quad * 8);
        o = __builtin_amdgcn_mfma_f32_16x16x32_bf16(af[ks], bfr, o, 0, 0, 0);
      }
      if (quad < 2) {  // rows 0..7 are the real tokens
        const float bn = bproj[n];
#pragma unroll
        for (int r = 0; r < 4; ++r)
          out[(size_t)(bt0 + quad * 4 + r) * CC + n] = o[r] + bn;
      }
    }
  }
}

// ---------------------------------------------------------------------------
extern "C" void kernel_launch(void* const* d_in, const int* in_sizes, int n_in,
                              void* d_out, int out_size, void* d_ws, size_t ws_size,
                              hipStream_t stream) {
  const float* x      = (const float*)d_in[0];
  const float* w_qkv  = (const float*)d_in[1];
  const float* b_qkv  = (const float*)d_in[2];
  const float* w_proj = (const float*)d_in[3];
  const float* b_proj = (const float*)d_in[4];
  float* outp = (float*)d_out;

  // ws layout (ushorts). 256 KB front guard absorbs attn's src<0 reads;
  // xb right after qkv absorbs src>=TT / Q-row overruns (finite bf16).
  ushort* base  = (ushort*)d_ws;
  ushort* qkv   = base + 131072;                   // MM x QKLD (Q | K)
  ushort* xb    = qkv + (size_t)MM * QKLD;         // MM x 512 (also back guard)
  ushort* wqb   = xb + (size_t)NX;                 // 1536 x 512
  ushort* wpb   = wqb + (size_t)NWQ;               // 512 x 512
  ushort* vTg   = wpb + (size_t)NWP;               // guard(64) + 512 x 4096 + guard(64)
  ushort* vT    = vTg + 64;

  // 0) convert fp32 inputs to bf16
  convert_bf16<<<(NX + NWQ + NWP) / (256 * 8), 256, 0, stream>>>(x, w_qkv, w_proj, xb, wqb, wpb);
  // 1) qkv = x @ w_qkv.T + b_qkv -> Q,K rows (ld 1024); V transposed to vT
  {
    dim3 grid((3 * CC) / 64, MM / 128);  // 24 x 32 = 768 blocks
    gemm_qkv<<<grid, 256, 0, stream>>>(xb, wqb, b_qkv, qkv, vT);
  }
  // 2) fused banded attention + projection -> fp32 out
  attn_proj<<<MM / ATILE, 256, 0, stream>>>(qkv, vT, wpb, b_proj, outp);
}

// Round 10
// 115.719 us; speedup vs baseline: 1.1483x; 1.1483x over previous
//
#include <hip/hip_runtime.h>
#include <math.h>

// LocalAttention: B=2, T=2048, C=512, WINDOW=32
#define BB 2
#define TT 2048
#define CC 512
#define WIN 32
#define WSZ 63            // 2*WIN-1
#define MM (BB * TT)      // 4096
#define QKLD 1024         // qkv intermediate row stride (Q | K only)

typedef __attribute__((ext_vector_type(8))) short short8;
typedef __attribute__((ext_vector_type(4))) float floatx4;

__device__ inline unsigned short bf16_rn(float f) {
  unsigned u = __builtin_bit_cast(unsigned, f);
  u += 0x7fff + ((u >> 16) & 1);
  return (unsigned short)(u >> 16);
}
__device__ inline unsigned pack_bf16x2(float lo, float hi) {
  return (unsigned)bf16_rn(lo) | ((unsigned)bf16_rn(hi) << 16);
}

// ---------------------------------------------------------------------------
// Pre-convert fp32 inputs -> bf16 (x, w_qkv, w_proj). 8 elems/thread.
// x-portion blocks are XCD-swizzled so each x m-slice converts on the XCD
// whose L2 will serve it to gemm_qkv.
// ---------------------------------------------------------------------------
#define NX  (MM * CC)          // 2097152
#define NWQ (3 * CC * CC)      // 786432
#define NWP (CC * CC)          // 262144
#define NXBLK (NX / 2048)      // 1024 x-blocks

__global__ __launch_bounds__(256) void convert_bf16(
    const float* __restrict__ x, const float* __restrict__ wq,
    const float* __restrict__ wp, ushort* __restrict__ xb,
    ushort* __restrict__ wqb, ushort* __restrict__ wpb) {
  int blk = blockIdx.x;
  if (blk < NXBLK) blk = ((blk & 7) << 7) | (blk >> 3);  // 8 XCDs x 128 blocks
  const size_t e = ((size_t)blk * 256 + threadIdx.x) * 8;
  const float* src;
  ushort* dst;
  size_t off;
  if (e < NX) { src = x; dst = xb; off = e; }
  else if (e < NX + NWQ) { src = wq; dst = wqb; off = e - NX; }
  else { src = wp; dst = wpb; off = e - NX - NWQ; }
  float4 v0 = ((const float4*)(src + off))[0];
  float4 v1 = ((const float4*)(src + off))[1];
  uint4 o;
  o.x = pack_bf16x2(v0.x, v0.y);
  o.y = pack_bf16x2(v0.z, v0.w);
  o.z = pack_bf16x2(v1.x, v1.y);
  o.w = pack_bf16x2(v1.z, v1.w);
  *(uint4*)(dst + off) = o;
}

// ---------------------------------------------------------------------------
// Barrier-light NT GEMM for QKV (r7 structure). BM=128, BN=64, K=512.
// 1-D grid 768, XCD-swizzled: XCD x owns m-rows [x*512, x*512+512) so its
// x-slice (0.5 MB) and the weight panel stay L2-resident; it also writes the
// qkv/vT m-range the matching attention XCD reads next.
// ---------------------------------------------------------------------------
#define PSTR 264   // B-panel k-stride (elems); 528B rows
#define VSTR 136   // V-transpose m-stride (elems)

__global__ __launch_bounds__(256) void gemm_qkv(
    const ushort* __restrict__ A, const ushort* __restrict__ B,
    const float* __restrict__ bias, ushort* __restrict__ C,
    ushort* __restrict__ VT) {
  __shared__ __align__(16) ushort Bs[64 * PSTR];  // 33792 B

  const int tid = threadIdx.x;
  const int lane = tid & 63;
  const int wave = tid >> 6;
  const int blk = blockIdx.x;              // 0..767
  const int xcd = blk & 7, j = blk >> 3;   // j: 0..95
  const int m0 = (xcd * 4 + (j & 3)) * 128;
  const int n0 = (j >> 2) * 64;            // 0..1472
  const int wm = wave * 32;
  const int mlane = lane & 15, quad = lane >> 4;

  floatx4 acc[2][4];
#pragma unroll
  for (int i = 0; i < 2; ++i)
#pragma unroll
    for (int jj = 0; jj < 4; ++jj) acc[i][jj] = (floatx4){0.f, 0.f, 0.f, 0.f};

  for (int h = 0; h < 2; ++h) {
    if (h) __syncthreads();
#pragma unroll
    for (int i = 0; i < 8; ++i) {
      const int idx = tid + 256 * i;
      const int r = idx >> 5, kc = (idx & 31) * 8;
      *(uint4*)(&Bs[r * PSTR + kc]) =
          *(const uint4*)(B + (size_t)(n0 + r) * CC + h * 256 + kc);
    }
    __syncthreads();
#pragma unroll
    for (int ks = 0; ks < 8; ++ks) {
      short8 bfr[4];
#pragma unroll
      for (int ni = 0; ni < 4; ++ni)
        bfr[ni] = *(const short8*)(&Bs[(ni * 16 + mlane) * PSTR + ks * 32 + quad * 8]);
#pragma unroll
      for (int mi = 0; mi < 2; ++mi) {
        short8 af = *(const short8*)(
            A + (size_t)(m0 + wm + mi * 16 + mlane) * CC + h * 256 + ks * 32 + quad * 8);
#pragma unroll
        for (int ni = 0; ni < 4; ++ni)
          acc[mi][ni] = __builtin_amdgcn_mfma_f32_16x16x32_bf16(af, bfr[ni], acc[mi][ni], 0, 0, 0);
      }
    }
  }

  // epilogue: D row = quad*4 + r (m), col = mlane (n)
  if (n0 < 1024) {  // Q,K path -> qkv rows (stride QKLD)
#pragma unroll
    for (int ni = 0; ni < 4; ++ni) {
      const int n = n0 + ni * 16 + mlane;
      const float bn = bias[n];
#pragma unroll
      for (int mi = 0; mi < 2; ++mi) {
        const int mbase = m0 + wm + mi * 16 + quad * 4;
#pragma unroll
        for (int r = 0; r < 4; ++r)
          C[(size_t)(mbase + r) * QKLD + n] = bf16_rn(acc[mi][ni][r] + bn);
      }
    }
  } else {  // V path: transpose through LDS, coalesced VT[n][m] rows
    ushort* Vt = Bs;  // alias; 64 x VSTR = 17408 B
    __syncthreads();
#pragma unroll
    for (int ni = 0; ni < 4; ++ni) {
      const int n_l = ni * 16 + mlane;
      const float bn = bias[n0 + n_l];
#pragma unroll
      for (int mi = 0; mi < 2; ++mi) {
        const int m_l = wm + mi * 16 + quad * 4;
        ushort4 pk;
        pk.x = bf16_rn(acc[mi][ni][0] + bn);
        pk.y = bf16_rn(acc[mi][ni][1] + bn);
        pk.z = bf16_rn(acc[mi][ni][2] + bn);
        pk.w = bf16_rn(acc[mi][ni][3] + bn);
        *(ushort4*)(&Vt[n_l * VSTR + m_l]) = pk;
      }
    }
    __syncthreads();
#pragma unroll
    for (int i = 0; i < 4; ++i) {  // 64 rows x 16 uint4
      const int idx = tid + 256 * i;
      const int n_l = idx >> 4, mo = (idx & 15) * 8;
      *(uint4*)(VT + (size_t)(n0 - 1024 + n_l) * MM + m0 + mo) =
          *(const uint4*)(&Vt[n_l * VSTR + mo]);
    }
  }
}

// ---------------------------------------------------------------------------
// Fused banded attention + projection. ATILE=16 real tokens per block,
// 512 threads (8 waves), grid 256, XCD-swizzled (XCD x owns a contiguous
// 512-token range -> K/vT/w_proj slices all L2-resident).
// Window rows r=0..95 (79 used), src = t0-32+r, tap j = r-1-row in [0,63).
//  scores: waves 0..5 each own one 16-row col-tile (full k=512).
//  softmax: 16 rows x 32 lanes, 3 cols each -> P bf16 (k-extent 96).
//  PV: 32 c-tiles / 8 waves, V direct from vT[c][m]; at tile -> LDS.
//  proj: 32 n-tiles / 8 waves, w_proj frags direct from L2; all rows real.
// OOB reads fault-safe via ws guards; garbage lands in masked/P=0 positions.
// ---------------------------------------------------------------------------
#define ATILE 16
#define SLD 100   // S row stride (floats)
#define PLD 104   // P row stride (ushorts), odd granules
#define ATS 520   // attn-tile row stride (ushorts), odd granules

__global__ __launch_bounds__(512) void attn_proj(
    const ushort* __restrict__ qkv, const ushort* __restrict__ vT,
    const ushort* __restrict__ wpb, const float* __restrict__ bproj,
    float* __restrict__ out) {
  __shared__ __align__(16) float s_s[16 * SLD];    //  6400 B
  __shared__ __align__(16) ushort p_s[16 * PLD];   //  3328 B
  __shared__ __align__(16) ushort at_s[16 * ATS];  // 16640 B

  const int tid = threadIdx.x;
  const int wave = tid >> 6, lane = tid & 63;
  const int mlane = lane & 15, quad = lane >> 4;
  const int blk = blockIdx.x;                       // 0..255
  const int grp = ((blk & 7) << 5) | (blk >> 3);    // XCD-contiguous groups
  const int bt0 = grp * ATILE;                      // 16 | 2048: no straddle
  const int b = bt0 / TT, t0 = bt0 % TT;
  const ushort* qbase = qkv + (size_t)b * TT * QKLD;

  // ---- scores: S[16][96] = Q.K^T; waves 0..5, one col-tile each ----
  if (wave < 6) {
    const ushort* qrow = qbase + (ptrdiff_t)(t0 + mlane) * QKLD;
    const ushort* krow = qbase + (ptrdiff_t)(t0 - 32 + wave * 16 + mlane) * QKLD + CC;
    floatx4 sa = (floatx4){0.f, 0.f, 0.f, 0.f}, sb = sa;
#pragma unroll
    for (int ks = 0; ks < 16; ++ks) {
      short8 a  = *(const short8*)(qrow + ks * 32 + quad * 8);
      short8 b0 = *(const short8*)(krow + ks * 32 + quad * 8);
      if (ks & 1) sb = __builtin_amdgcn_mfma_f32_16x16x32_bf16(a, b0, sb, 0, 0, 0);
      else        sa = __builtin_amdgcn_mfma_f32_16x16x32_bf16(a, b0, sa, 0, 0, 0);
    }
#pragma unroll
    for (int r = 0; r < 4; ++r)
      s_s[(quad * 4 + r) * SLD + wave * 16 + mlane] = sa[r] + sb[r];
  }
  __syncthreads();

  // ---- softmax: 16 rows x 32 lanes, 3 cols each; mask j = r-1-row ----
  {
    const int row = tid >> 5, l5 = tid & 31;
    const float inv_scale = 0.044194173824159216f;  // 512^-0.5
    float e[3];
    float mx = -INFINITY;
#pragma unroll
    for (int i = 0; i < 3; ++i) {
      const int r = l5 + 32 * i;
      const int j = r - 1 - row;
      const int src = t0 - 32 + r;
      const bool valid = (j >= 0) && (j < WSZ) && (src >= 0) && (src < TT);
      e[i] = valid ? s_s[row * SLD + r] * inv_scale : -INFINITY;
      mx = fmaxf(mx, e[i]);
    }
    mx = fmaxf(mx, __shfl_xor(mx, 1));  mx = fmaxf(mx, __shfl_xor(mx, 2));
    mx = fmaxf(mx, __shfl_xor(mx, 4));  mx = fmaxf(mx, __shfl_xor(mx, 8));
    mx = fmaxf(mx, __shfl_xor(mx, 16));
    float sum = 0.f;
#pragma unroll
    for (int i = 0; i < 3; ++i) {
      e[i] = (e[i] == -INFINITY) ? 0.f : __expf(e[i] - mx);
      sum += e[i];
    }
    sum += __shfl_xor(sum, 1); sum += __shfl_xor(sum, 2);
    sum += __shfl_xor(sum, 4); sum += __shfl_xor(sum, 8);
    sum += __shfl_xor(sum, 16);
    const float rs = 1.f / sum;
#pragma unroll
    for (int i = 0; i < 3; ++i)
      p_s[row * PLD + l5 + 32 * i] = bf16_rn(e[i] * rs);
    if (l5 < 8) p_s[row * PLD + 96 + l5] = 0;  // zero k-pad cols 96..103
  }
  __syncthreads();

  // ---- PV: at[16][512] = P.V (k=96), V direct from vT[c][m] ----
  const ptrdiff_t mcol0 = (ptrdiff_t)b * TT + t0 - 32;
  {
    short8 pa[3];
#pragma unroll
    for (int ks = 0; ks < 3; ++ks)
      pa[ks] = *(const short8*)(&p_s[mlane * PLD + ks * 32 + quad * 8]);
#pragma unroll
    for (int i = 0; i < 4; ++i) {
      const int nt = wave * 4 + i;  // c-tile 0..31
      const ushort* vrow = vT + (ptrdiff_t)(nt * 16 + mlane) * MM + mcol0;
      floatx4 o = (floatx4){0.f, 0.f, 0.f, 0.f};
#pragma unroll
      for (int ks = 0; ks < 3; ++ks) {
        short8 bv = *(const short8*)(vrow + ks * 32 + quad * 8);
        o = __builtin_amdgcn_mfma_f32_16x16x32_bf16(pa[ks], bv, o, 0, 0, 0);
      }
#pragma unroll
      for (int r = 0; r < 4; ++r)
        at_s[(quad * 4 + r) * ATS + nt * 16 + mlane] = bf16_rn(o[r]);
    }
  }
  __syncthreads();

  // ---- proj: out[16][512] = at @ w_proj^T + b_proj; all rows real ----
  {
    short8 af[16];
#pragma unroll
    for (int ks = 0; ks < 16; ++ks)
      af[ks] = *(const short8*)(&at_s[mlane * ATS + ks * 32 + quad * 8]);
#pragma unroll
    for (int i = 0; i < 4; ++i) {
      const int n = (wave * 4 + i) * 16 + mlane;
      const ushort* wrow = wpb + (size_t)n * CC;
      floatx4 o = (floatx4){0.f, 0.f, 0.f, 0.f};
#pragma unroll
      for (int ks = 0; ks < 16; ++ks) {
        short8 bfr = *(const short8*)(wrow + ks * 32 + quad * 8);
        o = __builtin_amdgcn_mfma_f32_16x16x32_bf16(af[ks], bfr, o, 0, 0, 0);
      }
      const float bn = bproj[n];
#pragma unroll
      for (int r = 0; r < 4; ++r)
        out[(size_t)(bt0 + quad * 4 + r) * CC + n] = o[r] + bn;
    }
  }
}

// ---------------------------------------------------------------------------
extern "C" void kernel_launch(void* const* d_in, const int* in_sizes, int n_in,
                              void* d_out, int out_size, void* d_ws, size_t ws_size,
                              hipStream_t stream) {
  const float* x      = (const float*)d_in[0];
  const float* w_qkv  = (const float*)d_in[1];
  const float* b_qkv  = (const float*)d_in[2];
  const float* w_proj = (const float*)d_in[3];
  const float* b_proj = (const float*)d_in[4];
  float* outp = (float*)d_out;

  // ws layout (ushorts). 256 KB front guard absorbs attn's src<0 reads;
  // xb right after qkv absorbs src>=TT overruns (finite bf16).
  ushort* base  = (ushort*)d_ws;
  ushort* qkv   = base + 131072;                   // MM x QKLD (Q | K)
  ushort* xb    = qkv + (size_t)MM * QKLD;         // MM x 512 (also back guard)
  ushort* wqb   = xb + (size_t)NX;                 // 1536 x 512
  ushort* wpb   = wqb + (size_t)NWQ;               // 512 x 512
  ushort* vTg   = wpb + (size_t)NWP;               // guard(64) + 512 x 4096 + guard(64)
  ushort* vT    = vTg + 64;

  // 0) convert fp32 inputs to bf16 (x portion XCD-swizzled)
  convert_bf16<<<(NX + NWQ + NWP) / (256 * 8), 256, 0, stream>>>(x, w_qkv, w_proj, xb, wqb, wpb);
  // 1) qkv = x @ w_qkv.T + b_qkv -> Q,K rows (ld 1024); V transposed to vT
  gemm_qkv<<<768, 256, 0, stream>>>(xb, wqb, b_qkv, qkv, vT);
  // 2) fused banded attention + projection -> fp32 out
  attn_proj<<<256, 512, 0, stream>>>(qkv, vT, wpb, b_proj, outp);
}

// Round 11
// 115.272 us; speedup vs baseline: 1.1528x; 1.0039x over previous
//
#include <hip/hip_runtime.h>
#include <math.h>

// LocalAttention: B=2, T=2048, C=512, WINDOW=32
#define BB 2
#define TT 2048
#define CC 512
#define WIN 32
#define WSZ 63            // 2*WIN-1
#define MM (BB * TT)      // 4096
#define QKLD 1024         // qkv intermediate row stride (Q | K only)

typedef __attribute__((ext_vector_type(8))) short short8;
typedef __attribute__((ext_vector_type(4))) float floatx4;

__device__ inline unsigned short bf16_rn(float f) {
  unsigned u = __builtin_bit_cast(unsigned, f);
  u += 0x7fff + ((u >> 16) & 1);
  return (unsigned short)(u >> 16);
}
__device__ inline unsigned pack_bf16x2(float lo, float hi) {
  return (unsigned)bf16_rn(lo) | ((unsigned)bf16_rn(hi) << 16);
}

// ---------------------------------------------------------------------------
// Pre-convert fp32 inputs -> bf16 (x, w_qkv, w_proj). 8 elems/thread.
// x-portion XCD-swizzled to match gemm_qkv's m-slice ownership.
// ---------------------------------------------------------------------------
#define NX  (MM * CC)          // 2097152
#define NWQ (3 * CC * CC)      // 786432
#define NWP (CC * CC)          // 262144
#define NXBLK (NX / 2048)      // 1024 x-blocks

__global__ __launch_bounds__(256) void convert_bf16(
    const float* __restrict__ x, const float* __restrict__ wq,
    const float* __restrict__ wp, ushort* __restrict__ xb,
    ushort* __restrict__ wqb, ushort* __restrict__ wpb) {
  int blk = blockIdx.x;
  if (blk < NXBLK) blk = ((blk & 7) << 7) | (blk >> 3);  // 8 XCDs x 128 blocks
  const size_t e = ((size_t)blk * 256 + threadIdx.x) * 8;
  const float* src;
  ushort* dst;
  size_t off;
  if (e < NX) { src = x; dst = xb; off = e; }
  else if (e < NX + NWQ) { src = wq; dst = wqb; off = e - NX; }
  else { src = wp; dst = wpb; off = e - NX - NWQ; }
  float4 v0 = ((const float4*)(src + off))[0];
  float4 v1 = ((const float4*)(src + off))[1];
  uint4 o;
  o.x = pack_bf16x2(v0.x, v0.y);
  o.y = pack_bf16x2(v0.z, v0.w);
  o.z = pack_bf16x2(v1.x, v1.y);
  o.w = pack_bf16x2(v1.z, v1.w);
  *(uint4*)(dst + off) = o;
}

// ---------------------------------------------------------------------------
// Barrier-light NT GEMM for QKV. BM=128, BN=64, K=512. Grid 768, XCD-swizzled
// (XCD x owns m-rows [x*512, x*512+512)). __launch_bounds__(256,3) raises the
// VGPR cap to ~170 so all 16 A-fragments of a k-half fly in ONE batch
// (explicit prefetch array) instead of compiler-throttled small batches.
// ---------------------------------------------------------------------------
#define PSTR 264   // B-panel k-stride (elems); 528B rows
#define VSTR 136   // V-transpose m-stride (elems)

__global__ __launch_bounds__(256, 3) void gemm_qkv(
    const ushort* __restrict__ A, const ushort* __restrict__ B,
    const float* __restrict__ bias, ushort* __restrict__ C,
    ushort* __restrict__ VT) {
  __shared__ __align__(16) ushort Bs[64 * PSTR];  // 33792 B

  const int tid = threadIdx.x;
  const int lane = tid & 63;
  const int wave = tid >> 6;
  const int blk = blockIdx.x;              // 0..767
  const int xcd = blk & 7, j = blk >> 3;   // j: 0..95
  const int m0 = (xcd * 4 + (j & 3)) * 128;
  const int n0 = (j >> 2) * 64;            // 0..1472
  const int wm = wave * 32;
  const int mlane = lane & 15, quad = lane >> 4;

  floatx4 acc[2][4];
#pragma unroll
  for (int i = 0; i < 2; ++i)
#pragma unroll
    for (int jj = 0; jj < 4; ++jj) acc[i][jj] = (floatx4){0.f, 0.f, 0.f, 0.f};

  for (int h = 0; h < 2; ++h) {
    if (h) __syncthreads();
    // stage B panel half: 64 rows x 256 k = 2048 uint4, coalesced
#pragma unroll
    for (int i = 0; i < 8; ++i) {
      const int idx = tid + 256 * i;
      const int r = idx >> 5, kc = (idx & 31) * 8;
      *(uint4*)(&Bs[r * PSTR + kc]) =
          *(const uint4*)(B + (size_t)(n0 + r) * CC + h * 256 + kc);
    }
    // prefetch ALL 16 A fragments of this half (independent 16B gathers,
    // issued while the B-staging drains toward the barrier)
    short8 apre[16];
#pragma unroll
    for (int ks = 0; ks < 8; ++ks)
#pragma unroll
      for (int mi = 0; mi < 2; ++mi)
        apre[ks * 2 + mi] = *(const short8*)(
            A + (size_t)(m0 + wm + mi * 16 + mlane) * CC + h * 256 + ks * 32 + quad * 8);
    __syncthreads();
#pragma unroll
    for (int ks = 0; ks < 8; ++ks) {
      short8 bfr[4];
#pragma unroll
      for (int ni = 0; ni < 4; ++ni)
        bfr[ni] = *(const short8*)(&Bs[(ni * 16 + mlane) * PSTR + ks * 32 + quad * 8]);
#pragma unroll
      for (int mi = 0; mi < 2; ++mi)
#pragma unroll
        for (int ni = 0; ni < 4; ++ni)
          acc[mi][ni] = __builtin_amdgcn_mfma_f32_16x16x32_bf16(
              apre[ks * 2 + mi], bfr[ni], acc[mi][ni], 0, 0, 0);
    }
  }

  // epilogue: D row = quad*4 + r (m), col = mlane (n)
  if (n0 < 1024) {  // Q,K path -> qkv rows (stride QKLD)
#pragma unroll
    for (int ni = 0; ni < 4; ++ni) {
      const int n = n0 + ni * 16 + mlane;
      const float bn = bias[n];
#pragma unroll
      for (int mi = 0; mi < 2; ++mi) {
        const int mbase = m0 + wm + mi * 16 + quad * 4;
#pragma unroll
        for (int r = 0; r < 4; ++r)
          C[(size_t)(mbase + r) * QKLD + n] = bf16_rn(acc[mi][ni][r] + bn);
      }
    }
  } else {  // V path: transpose through LDS, coalesced VT[n][m] rows
    ushort* Vt = Bs;  // alias; 64 x VSTR = 17408 B
    __syncthreads();
#pragma unroll
    for (int ni = 0; ni < 4; ++ni) {
      const int n_l = ni * 16 + mlane;
      const float bn = bias[n0 + n_l];
#pragma unroll
      for (int mi = 0; mi < 2; ++mi) {
        const int m_l = wm + mi * 16 + quad * 4;
        ushort4 pk;
        pk.x = bf16_rn(acc[mi][ni][0] + bn);
        pk.y = bf16_rn(acc[mi][ni][1] + bn);
        pk.z = bf16_rn(acc[mi][ni][2] + bn);
        pk.w = bf16_rn(acc[mi][ni][3] + bn);
        *(ushort4*)(&Vt[n_l * VSTR + m_l]) = pk;
      }
    }
    __syncthreads();
#pragma unroll
    for (int i = 0; i < 4; ++i) {  // 64 rows x 16 uint4
      const int idx = tid + 256 * i;
      const int n_l = idx >> 4, mo = (idx & 15) * 8;
      *(uint4*)(VT + (size_t)(n0 - 1024 + n_l) * MM + m0 + mo) =
          *(const uint4*)(&Vt[n_l * VSTR + mo]);
    }
  }
}

// ---------------------------------------------------------------------------
// Fused banded attention + projection. ATILE=16, 512 threads, grid 256,
// XCD-swizzled. __launch_bounds__(512,2) -> VGPR cap 256: each phase's
// operand set is prefetched into registers in ONE batch, then the MFMA
// chains run (dual-chained where serial).
// OOB reads fault-safe via ws guards; garbage lands in masked/P=0 positions.
// ---------------------------------------------------------------------------
#define ATILE 16
#define SLD 100   // S row stride (floats)
#define PLD 104   // P row stride (ushorts), odd granules
#define ATS 520   // attn-tile row stride (ushorts), odd granules

__global__ __launch_bounds__(512, 2) void attn_proj(
    const ushort* __restrict__ qkv, const ushort* __restrict__ vT,
    const ushort* __restrict__ wpb, const float* __restrict__ bproj,
    float* __restrict__ out) {
  __shared__ __align__(16) float s_s[16 * SLD];    //  6400 B
  __shared__ __align__(16) ushort p_s[16 * PLD];   //  3328 B
  __shared__ __align__(16) ushort at_s[16 * ATS];  // 16640 B

  const int tid = threadIdx.x;
  const int wave = tid >> 6, lane = tid & 63;
  const int mlane = lane & 15, quad = lane >> 4;
  const int blk = blockIdx.x;                       // 0..255
  const int grp = ((blk & 7) << 5) | (blk >> 3);    // XCD-contiguous groups
  const int bt0 = grp * ATILE;                      // 16 | 2048: no straddle
  const int b = bt0 / TT, t0 = bt0 % TT;
  const ushort* qbase = qkv + (size_t)b * TT * QKLD;

  // ---- scores: S[16][96] = Q.K^T; waves 0..5, one col-tile each ----
  if (wave < 6) {
    const ushort* qrow = qbase + (ptrdiff_t)(t0 + mlane) * QKLD;
    const ushort* krow = qbase + (ptrdiff_t)(t0 - 32 + wave * 16 + mlane) * QKLD + CC;
    short8 qa[16], ka[16];
#pragma unroll
    for (int ks = 0; ks < 16; ++ks) {
      qa[ks] = *(const short8*)(qrow + ks * 32 + quad * 8);
      ka[ks] = *(const short8*)(krow + ks * 32 + quad * 8);
    }
    floatx4 sa = (floatx4){0.f, 0.f, 0.f, 0.f}, sb = sa;
#pragma unroll
    for (int ks = 0; ks < 16; ks += 2) {
      sa = __builtin_amdgcn_mfma_f32_16x16x32_bf16(qa[ks], ka[ks], sa, 0, 0, 0);
      sb = __builtin_amdgcn_mfma_f32_16x16x32_bf16(qa[ks + 1], ka[ks + 1], sb, 0, 0, 0);
    }
#pragma unroll
    for (int r = 0; r < 4; ++r)
      s_s[(quad * 4 + r) * SLD + wave * 16 + mlane] = sa[r] + sb[r];
  }
  __syncthreads();

  // ---- softmax: 16 rows x 32 lanes, 3 cols each; mask j = r-1-row ----
  {
    const int row = tid >> 5, l5 = tid & 31;
    const float inv_scale = 0.044194173824159216f;  // 512^-0.5
    float e[3];
    float mx = -INFINITY;
#pragma unroll
    for (int i = 0; i < 3; ++i) {
      const int r = l5 + 32 * i;
      const int j = r - 1 - row;
      const int src = t0 - 32 + r;
      const bool valid = (j >= 0) && (j < WSZ) && (src >= 0) && (src < TT);
      e[i] = valid ? s_s[row * SLD + r] * inv_scale : -INFINITY;
      mx = fmaxf(mx, e[i]);
    }
    mx = fmaxf(mx, __shfl_xor(mx, 1));  mx = fmaxf(mx, __shfl_xor(mx, 2));
    mx = fmaxf(mx, __shfl_xor(mx, 4));  mx = fmaxf(mx, __shfl_xor(mx, 8));
    mx = fmaxf(mx, __shfl_xor(mx, 16));
    float sum = 0.f;
#pragma unroll
    for (int i = 0; i < 3; ++i) {
      e[i] = (e[i] == -INFINITY) ? 0.f : __expf(e[i] - mx);
      sum += e[i];
    }
    sum += __shfl_xor(sum, 1); sum += __shfl_xor(sum, 2);
    sum += __shfl_xor(sum, 4); sum += __shfl_xor(sum, 8);
    sum += __shfl_xor(sum, 16);
    const float rs = 1.f / sum;
#pragma unroll
    for (int i = 0; i < 3; ++i)
      p_s[row * PLD + l5 + 32 * i] = bf16_rn(e[i] * rs);
    if (l5 < 8) p_s[row * PLD + 96 + l5] = 0;  // zero k-pad cols 96..103
  }
  __syncthreads();

  // ---- PV: at[16][512] = P.V (k=96), V direct from vT[c][m] ----
  const ptrdiff_t mcol0 = (ptrdiff_t)b * TT + t0 - 32;
  {
    short8 pa[3];
#pragma unroll
    for (int ks = 0; ks < 3; ++ks)
      pa[ks] = *(const short8*)(&p_s[mlane * PLD + ks * 32 + quad * 8]);
    // prefetch all 12 V fragments (4 c-tiles x 3 k-steps)
    short8 vv[4][3];
#pragma unroll
    for (int i = 0; i < 4; ++i) {
      const ushort* vrow = vT + (ptrdiff_t)((wave * 4 + i) * 16 + mlane) * MM + mcol0;
#pragma unroll
      for (int ks = 0; ks < 3; ++ks)
        vv[i][ks] = *(const short8*)(vrow + ks * 32 + quad * 8);
    }
#pragma unroll
    for (int i = 0; i < 4; ++i) {
      const int nt = wave * 4 + i;  // c-tile 0..31
      floatx4 o = (floatx4){0.f, 0.f, 0.f, 0.f};
#pragma unroll
      for (int ks = 0; ks < 3; ++ks)
        o = __builtin_amdgcn_mfma_f32_16x16x32_bf16(pa[ks], vv[i][ks], o, 0, 0, 0);
#pragma unroll
      for (int r = 0; r < 4; ++r)
        at_s[(quad * 4 + r) * ATS + nt * 16 + mlane] = bf16_rn(o[r]);
    }
  }
  __syncthreads();

  // ---- proj: out[16][512] = at @ w_proj^T + b_proj; all rows real ----
  {
    short8 af[16];
#pragma unroll
    for (int ks = 0; ks < 16; ++ks)
      af[ks] = *(const short8*)(&at_s[mlane * ATS + ks * 32 + quad * 8]);
#pragma unroll
    for (int i = 0; i < 4; ++i) {
      const int n = (wave * 4 + i) * 16 + mlane;
      const ushort* wrow = wpb + (size_t)n * CC;
      short8 bfr[16];
#pragma unroll
      for (int ks = 0; ks < 16; ++ks)
        bfr[ks] = *(const short8*)(wrow + ks * 32 + quad * 8);
      floatx4 oa = (floatx4){0.f, 0.f, 0.f, 0.f}, ob = oa;
#pragma unroll
      for (int ks = 0; ks < 16; ks += 2) {
        oa = __builtin_amdgcn_mfma_f32_16x16x32_bf16(af[ks], bfr[ks], oa, 0, 0, 0);
        ob = __builtin_amdgcn_mfma_f32_16x16x32_bf16(af[ks + 1], bfr[ks + 1], ob, 0, 0, 0);
      }
      const float bn = bproj[n];
#pragma unroll
      for (int r = 0; r < 4; ++r)
        out[(size_t)(bt0 + quad * 4 + r) * CC + n] = oa[r] + ob[r] + bn;
    }
  }
}

// ---------------------------------------------------------------------------
extern "C" void kernel_launch(void* const* d_in, const int* in_sizes, int n_in,
                              void* d_out, int out_size, void* d_ws, size_t ws_size,
                              hipStream_t stream) {
  const float* x      = (const float*)d_in[0];
  const float* w_qkv  = (const float*)d_in[1];
  const float* b_qkv  = (const float*)d_in[2];
  const float* w_proj = (const float*)d_in[3];
  const float* b_proj = (const float*)d_in[4];
  float* outp = (float*)d_out;

  // ws layout (ushorts). 256 KB front guard absorbs attn's src<0 reads;
  // xb right after qkv absorbs src>=TT overruns (finite bf16).
  ushort* base  = (ushort*)d_ws;
  ushort* qkv   = base + 131072;                   // MM x QKLD (Q | K)
  ushort* xb    = qkv + (size_t)MM * QKLD;         // MM x 512 (also back guard)
  ushort* wqb   = xb + (size_t)NX;                 // 1536 x 512
  ushort* wpb   = wqb + (size_t)NWQ;               // 512 x 512
  ushort* vTg   = wpb + (size_t)NWP;               // guard(64) + 512 x 4096 + guard(64)
  ushort* vT    = vTg + 64;

  // 0) convert fp32 inputs to bf16 (x portion XCD-swizzled)
  convert_bf16<<<(NX + NWQ + NWP) / (256 * 8), 256, 0, stream>>>(x, w_qkv, w_proj, xb, wqb, wpb);
  // 1) qkv = x @ w_qkv.T + b_qkv -> Q,K rows (ld 1024); V transposed to vT
  gemm_qkv<<<768, 256, 0, stream>>>(xb, wqb, b_qkv, qkv, vT);
  // 2) fused banded attention + projection -> fp32 out
  attn_proj<<<256, 512, 0, stream>>>(qkv, vT, wpb, b_proj, outp);
}